// Round 1
// baseline (232.751 us; speedup 1.0000x reference)
//
#include <hip/hip_runtime.h>
#include <math.h>

#define NROWS 16384   // B*T
#define DDIM  2048
#define NEXP  16
#define RBLOCKS 512   // router grid: 32 rows/block, 2 blocks/CU, fully resident
#define WPB 8         // waves per 512-thread block
#define ZN (RBLOCKS * WPB)

__device__ __forceinline__ float fnoise(float x) {
    return copysignf(sqrtf(fabsf(x)), x);
}

// async 16B global -> LDS (no VGPR round-trip). Pass the wave-uniform LDS
// base; HW adds lane*16. Source pointer includes +lane.
__device__ __forceinline__ void async_copy16(const float4* g, float4* l) {
    __builtin_amdgcn_global_load_lds(
        (const __attribute__((address_space(1))) void*)g,
        (__attribute__((address_space(3))) void*)l, 16, 0, 0);
}

// ws layout (float idx):
//   [0, 32768)       w_noisy [E][D]
//   [32768, 32784)   b_noisy [E]
//   32792            ctr (uint) — router arrival counter, zeroed by prep
//   [32800, 36896)   zpartial [ZN] (one float per wave)

// Vectorized prep: 8192 threads x float4 (was 32768 x scalar). Same per-
// element expression as the verified scalar version -> bitwise-compatible.
__global__ void prep_kernel(const float* __restrict__ weight,
                            const float* __restrict__ sigma_weight,
                            const float* __restrict__ bias,
                            const float* __restrict__ sigma_bias,
                            const float* __restrict__ eps_in,
                            const float* __restrict__ eps_out,
                            float* __restrict__ w_noisy,
                            float* __restrict__ b_noisy,
                            unsigned int* __restrict__ ctr) {
    int gid = blockIdx.x * blockDim.x + threadIdx.x;   // 0 .. 8191 (float4 idx)
    int e  = gid >> 9;          // 512 float4 per expert row
    int c4 = gid & 511;         // float4 column
    float4 w  = ((const float4*)weight)[gid];
    float4 sw = ((const float4*)sigma_weight)[gid];
    float4 ei = ((const float4*)eps_in)[c4];
    float fo = fnoise(eps_out[e]);
    float4 r;
    r.x = w.x + sw.x * fo * fnoise(ei.x);
    r.y = w.y + sw.y * fo * fnoise(ei.y);
    r.z = w.z + sw.z * fo * fnoise(ei.z);
    r.w = w.w + sw.w * fo * fnoise(ei.w);
    ((float4*)w_noisy)[gid] = r;
    if (gid < 4) {   // experts 4*gid .. 4*gid+3
        float4 b  = ((const float4*)bias)[gid];
        float4 sb = ((const float4*)sigma_bias)[gid];
        float4 eo = ((const float4*)eps_out)[gid];
        float4 rb;
        rb.x = b.x + sb.x * fnoise(eo.x);
        rb.y = b.y + sb.y * fnoise(eo.y);
        rb.z = b.z + sb.z * fnoise(eo.z);
        rb.w = b.w + sb.w * fnoise(eo.w);
        ((float4*)b_noisy)[gid] = rb;
    }
    if (gid == 8191) *ctr = 0u;   // arm the router arrival counter
}

// Block: 512 threads = 8 waves; wave wv owns 4 rows. D split in 8 chunks of
// 256 cols, grouped in 4 quarters of 512 cols. w double-buffered in LDS at
// quarter granularity (2 x 32 KiB): stage q+1 right after the quarter-q
// barrier (other buffer -> no hazard), compute 2 chunks (512 FMAs/wave)
// barrier-free, one barrier per quarter. x prefetched one chunk ahead in
// registers. 2 blocks/CU co-resident. Last-arriving block reduces the z-loss
// partials (fused finalize: saves a launch + graph dependency).
__global__ __launch_bounds__(512, 4) void router_kernel(
        const float* __restrict__ x,        // [NROWS][DDIM]
        const float* __restrict__ w_noisy,  // [E][D]
        const float* __restrict__ b_noisy,  // [E]
        float* __restrict__ out_router,     // [NROWS][E]
        float* __restrict__ out_idx,        // [NROWS][2] stored as float
        float* __restrict__ zpart,          // [ZN]
        float* __restrict__ out_z,          // scalar z-loss slot
        unsigned int* __restrict__ ctr) {   // arrival counter (prep zeroed)
    __shared__ float4 wlds[2][NEXP * 128];  // 2 x 32 KiB quarters, [16][128] float4
    __shared__ unsigned int lastFlag;
    __shared__ float ws8[WPB];

    const int tid  = threadIdx.x;
    const int wv   = tid >> 6;
    const int lane = tid & 63;

    const int rowBase = blockIdx.x * 32 + wv * 4;
    const float4* xr0 = (const float4*)(x + (size_t)(rowBase + 0) * DDIM);
    const float4* xr1 = (const float4*)(x + (size_t)(rowBase + 1) * DDIM);
    const float4* xr2 = (const float4*)(x + (size_t)(rowBase + 2) * DDIM);
    const float4* xr3 = (const float4*)(x + (size_t)(rowBase + 3) * DDIM);
    const float4* wsrc = (const float4*)w_noisy;  // [16][512] float4

    float acc[64];
    #pragma unroll
    for (int i = 0; i < 64; ++i) acc[i] = 0.0f;

    float4 xbuf[2][4];

    // ---- prologue: stage quarter 0 -> wlds[0] (16x128 float4, 4/thread)
    #pragma unroll
    for (int j = 0; j < 4; ++j) {
        int fb = j * 512 + wv * 64;
        async_copy16(wsrc + (size_t)(fb >> 7) * 512 + (fb & 127) + lane,
                     &wlds[0][fb]);
    }
    xbuf[0][0] = xr0[lane];
    xbuf[0][1] = xr1[lane];
    xbuf[0][2] = xr2[lane];
    xbuf[0][3] = xr3[lane];
    __syncthreads();   // quarter 0 in LDS (vmcnt(0) drain), x0 landed

    #pragma unroll
    for (int q = 0; q < 4; ++q) {
        const int cb = q & 1;
        const int nb = cb ^ 1;
        if (q < 3) {
            // stage quarter q+1 into the other buffer; latency covered by
            // the 512 FMAs/wave below, landed at the end-of-quarter barrier
            #pragma unroll
            for (int j = 0; j < 4; ++j) {
                int fb = j * 512 + wv * 64;
                async_copy16(wsrc + (size_t)(fb >> 7) * 512 + (q + 1) * 128
                                 + (fb & 127) + lane,
                             &wlds[nb][fb]);
            }
        }
        #pragma unroll
        for (int h = 0; h < 2; ++h) {       // chunk c = 2q + h
            const int c = 2 * q + h;
            const int xc = c & 1;
            const int xn = xc ^ 1;
            if (c < 7) {
                // x prefetch for chunk c+1 (consumed next chunk)
                int p = (c + 1) * 64 + lane;
                xbuf[xn][0] = xr0[p];
                xbuf[xn][1] = xr1[p];
                xbuf[xn][2] = xr2[p];
                xbuf[xn][3] = xr3[p];
            }
            #pragma unroll
            for (int e = 0; e < 16; ++e) {
                float4 w = wlds[cb][e * 128 + h * 64 + lane];
                float s0 = acc[0 * 16 + e];
                float s1 = acc[1 * 16 + e];
                float s2 = acc[2 * 16 + e];
                float s3 = acc[3 * 16 + e];
                s0 = fmaf(xbuf[xc][0].x, w.x, s0); s0 = fmaf(xbuf[xc][0].y, w.y, s0);
                s0 = fmaf(xbuf[xc][0].z, w.z, s0); s0 = fmaf(xbuf[xc][0].w, w.w, s0);
                s1 = fmaf(xbuf[xc][1].x, w.x, s1); s1 = fmaf(xbuf[xc][1].y, w.y, s1);
                s1 = fmaf(xbuf[xc][1].z, w.z, s1); s1 = fmaf(xbuf[xc][1].w, w.w, s1);
                s2 = fmaf(xbuf[xc][2].x, w.x, s2); s2 = fmaf(xbuf[xc][2].y, w.y, s2);
                s2 = fmaf(xbuf[xc][2].z, w.z, s2); s2 = fmaf(xbuf[xc][2].w, w.w, s2);
                s3 = fmaf(xbuf[xc][3].x, w.x, s3); s3 = fmaf(xbuf[xc][3].y, w.y, s3);
                s3 = fmaf(xbuf[xc][3].z, w.z, s3); s3 = fmaf(xbuf[xc][3].w, w.w, s3);
                acc[0 * 16 + e] = s0;
                acc[1 * 16 + e] = s1;
                acc[2 * 16 + e] = s2;
                acc[3 * 16 + e] = s3;
            }
        }
        if (q < 3) __syncthreads();   // q+1 landed; all waves done with q
    }

    // Butterfly transpose-reduce: lane l ends with full sum of index l
    // (l = r*16 + e over this wave's 4 rows x 16 experts).
    #pragma unroll
    for (int half = 32; half >= 1; half >>= 1) {
        #pragma unroll
        for (int i = 0; i < half; ++i) {
            bool hi = (lane & half) != 0;
            float keep = hi ? acc[i + half] : acc[i];
            float send = hi ? acc[i] : acc[i + half];
            float recv = __shfl_xor(send, half, 64);
            acc[i] = keep + recv;
        }
    }

    const int e = lane & 15;           // expert owned by this lane
    const int r = lane >> 4;           // local row 0..3
    const int row = rowBase + r;
    float logit = acc[0] + b_noisy[e];

    // top-1 with lower-index tie-break within the 16-lane group
    float m1 = logit; int i1 = e;
    #pragma unroll
    for (int off = 8; off >= 1; off >>= 1) {
        float om = __shfl_xor(m1, off, 64);
        int   oi = __shfl_xor(i1, off, 64);
        if (om > m1 || (om == m1 && oi < i1)) { m1 = om; i1 = oi; }
    }
    // top-2: mask out i1
    float v2 = (e == i1) ? -3.4e38f : logit;
    float m2 = v2; int i2 = e;
    #pragma unroll
    for (int off = 8; off >= 1; off >>= 1) {
        float om = __shfl_xor(m2, off, 64);
        int   oi = __shfl_xor(i2, off, 64);
        if (om > m2 || (om == m2 && oi < i2)) { m2 = om; i2 = oi; }
    }

    // softmax over sparse logits: exp(-1e30 - m1) == 0 exactly, so only
    // positions i1, i2 are nonzero.
    float t = expf(m2 - m1);
    float p1 = 1.0f / (1.0f + t);
    float val = (e == i1) ? p1 : ((e == i2) ? t * p1 : 0.0f);
    out_router[(size_t)rowBase * NEXP + lane] = val;   // fully coalesced

    if (e < 2) {
        out_idx[(size_t)row * 2 + e] = (float)((e == 0) ? i1 : i2);
    }

    // z-loss partial: sum lse^2 over this wave's 4 rows, no atomics.
    float zv = 0.0f;
    if (e == 0) {
        float lse = m1 + log1pf(t);
        zv = lse * lse;
    }
    zv += __shfl_xor(zv, 16, 64);
    zv += __shfl_xor(zv, 32, 64);
    if (lane == 0) {
        zpart[blockIdx.x * WPB + wv] = zv;
    }

    // ---- fused finalize: last-arriving block reduces zpart (canonical
    // split-K tail: stores drained by syncthreads, release via
    // threadfence+atomicAdd, acquire via threadfence on the reader).
    __syncthreads();                     // all 8 zpart stores of this block done
    if (tid == 0) {
        __threadfence();                 // publish zpart before the counter bump
        unsigned int prev = atomicAdd(ctr, 1u);
        lastFlag = (prev == RBLOCKS - 1u) ? 1u : 0u;
    }
    __syncthreads();
    if (lastFlag != 0u) {                // block-uniform
        __threadfence();                 // invalidate stale caches before reads
        float s = 0.0f;
        for (int i = tid; i < ZN; i += 512) s += zpart[i];   // 8 per thread
        #pragma unroll
        for (int off = 32; off >= 1; off >>= 1) s += __shfl_xor(s, off, 64);
        if (lane == 0) ws8[wv] = s;
        __syncthreads();
        if (tid == 0) {
            float total = 0.0f;
            #pragma unroll
            for (int i = 0; i < WPB; ++i) total += ws8[i];
            out_z[0] = total * (1.0f / (float)NROWS);
        }
    }
}

extern "C" void kernel_launch(void* const* d_in, const int* in_sizes, int n_in,
                              void* d_out, int out_size, void* d_ws, size_t ws_size,
                              hipStream_t stream) {
    const float* mh      = (const float*)d_in[0];
    const float* weight  = (const float*)d_in[1];
    const float* sigw    = (const float*)d_in[2];
    const float* bias    = (const float*)d_in[3];
    const float* sigb    = (const float*)d_in[4];
    const float* eps_in  = (const float*)d_in[5];
    const float* eps_out = (const float*)d_in[6];

    float* out      = (float*)d_out;
    float* w_noisy  = (float*)d_ws;
    float* b_noisy  = w_noisy + NEXP * DDIM;            // float idx 32768
    unsigned int* ctr = (unsigned int*)(w_noisy + 32792);
    float* zpart    = w_noisy + 32800;                  // 128B-aligned

    prep_kernel<<<32, 256, 0, stream>>>(
        weight, sigw, bias, sigb, eps_in, eps_out, w_noisy, b_noisy, ctr);

    router_kernel<<<RBLOCKS, 512, 0, stream>>>(
        mh, w_noisy, b_noisy, out, out + NROWS * NEXP, zpart,
        out + NROWS * NEXP + NROWS * 2, ctr);
}